// Round 9
// baseline (274.993 us; speedup 1.0000x reference)
//
#include <hip/hip_runtime.h>
#include <hip/hip_bf16.h>
#include <math.h>

#define D_MODEL 1024
#define SEQ 1024
#define BATCH 16
#define NROWS (BATCH * SEQ)   // 16384
#define KT8 8                 // K-tiles of 128 fp8

typedef float f32x4 __attribute__((ext_vector_type(4)));
typedef int   i32x4 __attribute__((ext_vector_type(4)));
typedef int   i32x8 __attribute__((ext_vector_type(8)));
typedef __hip_bfloat16 bf16;
typedef unsigned char u8;

__device__ __forceinline__ float bf2f(bf16 v) { return __bfloat162float(v); }
__device__ __forceinline__ bf16 f2bf(float v) { return __float2bfloat16(v); }

__device__ __forceinline__ void gload_lds16(const u8* g, u8* l) {
    __builtin_amdgcn_global_load_lds(
        (const __attribute__((address_space(1))) void*)g,
        (__attribute__((address_space(3))) void*)l, 16, 0, 0);
}

// pack 4 floats -> 4 fp8 e4m3 bytes (OCP on gfx950)
__device__ __forceinline__ int pk_fp8x4(float a, float b, float c, float d) {
    int r = __builtin_amdgcn_cvt_pk_fp8_f32(a, b, 0, false);
    r = __builtin_amdgcn_cvt_pk_fp8_f32(c, d, r, true);
    return r;
}

// 1024 blocks -> 8 XCDs x 128: each XCD a 16-row M-band swept over 8 N-tiles.
__device__ __forceinline__ void tile_coords128(int lin, int& m0, int& n0) {
    const int xcd = lin & 7;
    const int loc = lin >> 3;            // 0..127
    m0 = (xcd * 16 + (loc & 15)) * 128;
    n0 = (loc >> 4) * 128;
}

// ---------------- all 4 weights fp32 -> fp8, one dispatch ----------------
__global__ void conv_w4_kernel(const float* __restrict__ s0, const float* __restrict__ s1,
                               const float* __restrict__ s2, const float* __restrict__ s3,
                               u8* __restrict__ dst) {
    const float* srcs[4] = {s0, s1, s2, s3};
    const float* src = srcs[blockIdx.y];
    int* d = reinterpret_cast<int*>(dst + (size_t)blockIdx.y * (D_MODEL * D_MODEL));
    int i = blockIdx.x * blockDim.x + threadIdx.x;
    const int stride = gridDim.x * blockDim.x;
    for (; i < (D_MODEL * D_MODEL) / 4; i += stride) {
        float4 f = reinterpret_cast<const float4*>(src)[i];
        d[i] = pk_fp8x4(f.x, f.y, f.z, f.w);
    }
}

// ---------------- fused LayerNorm + time-mix -> fp8, 4 rows per wave ----------------
// Row-chained: cn of row r serves as prev_norm of row r+1; 5 row-loads / 4 rows.
__global__ __launch_bounds__(256) void lnmix_kernel(
    const float* __restrict__ x, const float* __restrict__ gamma, const float* __restrict__ beta,
    const float* __restrict__ tmk, const float* __restrict__ tmv, const float* __restrict__ tmr,
    u8* __restrict__ xk, u8* __restrict__ xv, u8* __restrict__ xr)
{
    const int wave = threadIdx.x >> 6, lane = threadIdx.x & 63;
    const int lb = (blockIdx.x & 7) * (gridDim.x >> 3) + (blockIdx.x >> 3);
    const int row0 = (lb * 4 + wave) * 4;       // first of 4 rows
    const int t0 = row0 & (SEQ - 1);

    // row-invariant params
    float4 g[4], b[4], mk[4], mv[4], mr[4];
#pragma unroll
    for (int c = 0; c < 4; c++) {
        const int d = lane * 4 + c * 256;
        g[c]  = *reinterpret_cast<const float4*>(gamma + d);
        b[c]  = *reinterpret_cast<const float4*>(beta + d);
        mk[c] = *reinterpret_cast<const float4*>(tmk + d);
        mv[c] = *reinterpret_cast<const float4*>(tmv + d);
        mr[c] = *reinterpret_cast<const float4*>(tmr + d);
    }

    float4 pcn[4];   // normalized prev row (gamma/beta applied)
    if (t0 == 0) {
#pragma unroll
        for (int c = 0; c < 4; c++) pcn[c] = make_float4(0.f, 0.f, 0.f, 0.f);
    } else {
        const size_t pb = (size_t)(row0 - 1) * D_MODEL;
        float4 vp[4];
        float s = 0.f, s2 = 0.f;
#pragma unroll
        for (int c = 0; c < 4; c++) {
            vp[c] = *reinterpret_cast<const float4*>(x + pb + lane * 4 + c * 256);
            s  += vp[c].x + vp[c].y + vp[c].z + vp[c].w;
            s2 += vp[c].x * vp[c].x + vp[c].y * vp[c].y + vp[c].z * vp[c].z + vp[c].w * vp[c].w;
        }
#pragma unroll
        for (int off = 1; off < 64; off <<= 1) { s += __shfl_xor(s, off); s2 += __shfl_xor(s2, off); }
        const float mu = s * (1.0f / D_MODEL);
        const float rs = rsqrtf(s2 * (1.0f / D_MODEL) - mu * mu + 1e-5f);
#pragma unroll
        for (int c = 0; c < 4; c++) {
            pcn[c].x = (vp[c].x - mu) * rs * g[c].x + b[c].x;
            pcn[c].y = (vp[c].y - mu) * rs * g[c].y + b[c].y;
            pcn[c].z = (vp[c].z - mu) * rs * g[c].z + b[c].z;
            pcn[c].w = (vp[c].w - mu) * rs * g[c].w + b[c].w;
        }
    }

#pragma unroll 1
    for (int r = 0; r < 4; ++r) {
        const size_t base = (size_t)(row0 + r) * D_MODEL;
        float4 vc[4];
        float s = 0.f, s2 = 0.f;
#pragma unroll
        for (int c = 0; c < 4; c++) {
            vc[c] = *reinterpret_cast<const float4*>(x + base + lane * 4 + c * 256);
            s  += vc[c].x + vc[c].y + vc[c].z + vc[c].w;
            s2 += vc[c].x * vc[c].x + vc[c].y * vc[c].y + vc[c].z * vc[c].z + vc[c].w * vc[c].w;
        }
#pragma unroll
        for (int off = 1; off < 64; off <<= 1) { s += __shfl_xor(s, off); s2 += __shfl_xor(s2, off); }
        const float mu = s * (1.0f / D_MODEL);
        const float rs = rsqrtf(s2 * (1.0f / D_MODEL) - mu * mu + 1e-5f);
#pragma unroll
        for (int c = 0; c < 4; c++) {
            const int d = lane * 4 + c * 256;
            float cn[4], pn[4], kk[4], vv[4], rr[4];
            cn[0] = (vc[c].x - mu) * rs * g[c].x + b[c].x;
            cn[1] = (vc[c].y - mu) * rs * g[c].y + b[c].y;
            cn[2] = (vc[c].z - mu) * rs * g[c].z + b[c].z;
            cn[3] = (vc[c].w - mu) * rs * g[c].w + b[c].w;
            pn[0] = pcn[c].x; pn[1] = pcn[c].y; pn[2] = pcn[c].z; pn[3] = pcn[c].w;
            const float mkv[4] = {mk[c].x, mk[c].y, mk[c].z, mk[c].w};
            const float mvv[4] = {mv[c].x, mv[c].y, mv[c].z, mv[c].w};
            const float mrv[4] = {mr[c].x, mr[c].y, mr[c].z, mr[c].w};
#pragma unroll
            for (int e = 0; e < 4; e++) {
                kk[e] = mkv[e] * cn[e] + (1.0f - mkv[e]) * pn[e];
                vv[e] = mvv[e] * cn[e] + (1.0f - mvv[e]) * pn[e];
                rr[e] = mrv[e] * cn[e] + (1.0f - mrv[e]) * pn[e];
            }
            *reinterpret_cast<int*>(xk + base + d) = pk_fp8x4(kk[0], kk[1], kk[2], kk[3]);
            *reinterpret_cast<int*>(xv + base + d) = pk_fp8x4(vv[0], vv[1], vv[2], vv[3]);
            *reinterpret_cast<int*>(xr + base + d) = pk_fp8x4(rr[0], rr[1], rr[2], rr[3]);
            pcn[c].x = cn[0]; pcn[c].y = cn[1]; pcn[c].z = cn[2]; pcn[c].w = cn[3];
        }
    }
}

// ============================================================================
// DUAL 128x128 fp8 MX GEMM core (R7 conflict-free chunk permutation, measured
// 0 conflicts). Optional PFX: prefetch the residual x tile into registers at
// kt=4/5 so the epilogue's 64 MB x-read overlaps the K-loop (store-only tail).
// ============================================================================
template <bool PFX>
__device__ __forceinline__ void gemm128_fp8_dual(
    const u8* __restrict__ A0, const u8* __restrict__ W0,
    const u8* __restrict__ A1, const u8* __restrict__ W1,
    u8* __restrict__ lds, int m0, int n0,
    f32x4 (&acc0)[4][4], f32x4 (&acc1)[4][4],
    const float* __restrict__ xg, float* xr_)
{
    const int tid  = threadIdx.x;
    const int wave = tid >> 6, lane = tid & 63;
    const int wm = wave >> 1, wn = wave & 1;
    const int mf = lane & 15, quad = lane >> 4;
    const int srow = tid >> 3;                         // 0..31
    const int u  = (tid & 7) ^ (srow & 7);
    const int sw = (((u & 3) << 1) | (u >> 2)) * 16;   // source data chunk (bytes)

    const u8* A0g = A0 + (size_t)(m0 + srow) * D_MODEL + sw;
    const u8* B0g = W0 + (size_t)(n0 + srow) * D_MODEL + sw;
    const u8* A1g = A1 + (size_t)(m0 + srow) * D_MODEL + sw;
    const u8* B1g = W1 + (size_t)(n0 + srow) * D_MODEL + sw;

    u8* As0 = lds;
    u8* Bs0 = lds + 16384;
    u8* As1 = lds + 32768;
    u8* Bs1 = lds + 49152;

    const int swz0 = ((quad)     ^ (mf & 7)) * 16;
    const int swz1 = ((4 + quad) ^ (mf & 7)) * 16;
    const int aRow = (wm * 64 + mf) * 128;
    const int bRow = (wn * 64 + mf) * 128;

#pragma unroll 1
    for (int kt = 0; kt < KT8; ++kt) {
        __syncthreads();
#pragma unroll
        for (int g = 0; g < 4; ++g) {
            const size_t go = (size_t)g * 32 * D_MODEL + kt * 128;
            const int lo = g * 4096 + wave * 1024;
            gload_lds16(A0g + go, As0 + lo);
            gload_lds16(B0g + go, Bs0 + lo);
            gload_lds16(A1g + go, As1 + lo);
            gload_lds16(B1g + go, Bs1 + lo);
        }
        if (PFX && (kt == 4 || kt == 5)) {
            const int i0 = (kt == 4) ? 0 : 2;
#pragma unroll
            for (int i = 0; i < 2; ++i)
#pragma unroll
                for (int j = 0; j < 4; ++j)
#pragma unroll
                    for (int e = 0; e < 4; ++e) {
                        const int row = m0 + wm * 64 + (i0 + i) * 16 + quad * 4 + e;
                        const int col = n0 + wn * 64 + j * 16 + mf;
                        xr_[(i0 + i) * 16 + j * 4 + e] = xg[(size_t)row * D_MODEL + col];
                    }
            asm volatile("" ::: "memory");   // pin issue point: don't sink to epilogue
        }
        __syncthreads();

        i32x8 af[4], bf[4];
        // ---- GEMM 0 ----
#pragma unroll
        for (int i = 0; i < 4; ++i) {
            i32x4 lo = *reinterpret_cast<const i32x4*>(As0 + aRow + i * 2048 + swz0);
            i32x4 hi = *reinterpret_cast<const i32x4*>(As0 + aRow + i * 2048 + swz1);
            af[i] = __builtin_shufflevector(lo, hi, 0, 1, 2, 3, 4, 5, 6, 7);
        }
#pragma unroll
        for (int j = 0; j < 4; ++j) {
            i32x4 lo = *reinterpret_cast<const i32x4*>(Bs0 + bRow + j * 2048 + swz0);
            i32x4 hi = *reinterpret_cast<const i32x4*>(Bs0 + bRow + j * 2048 + swz1);
            bf[j] = __builtin_shufflevector(lo, hi, 0, 1, 2, 3, 4, 5, 6, 7);
        }
#pragma unroll
        for (int i = 0; i < 4; ++i)
#pragma unroll
            for (int j = 0; j < 4; ++j)
                acc0[i][j] = __builtin_amdgcn_mfma_scale_f32_16x16x128_f8f6f4(
                    af[i], bf[j], acc0[i][j], 0, 0, 0, 127, 0, 127);
        // ---- GEMM 1 ----
#pragma unroll
        for (int i = 0; i < 4; ++i) {
            i32x4 lo = *reinterpret_cast<const i32x4*>(As1 + aRow + i * 2048 + swz0);
            i32x4 hi = *reinterpret_cast<const i32x4*>(As1 + aRow + i * 2048 + swz1);
            af[i] = __builtin_shufflevector(lo, hi, 0, 1, 2, 3, 4, 5, 6, 7);
        }
#pragma unroll
        for (int j = 0; j < 4; ++j) {
            i32x4 lo = *reinterpret_cast<const i32x4*>(Bs1 + bRow + j * 2048 + swz0);
            i32x4 hi = *reinterpret_cast<const i32x4*>(Bs1 + bRow + j * 2048 + swz1);
            bf[j] = __builtin_shufflevector(lo, hi, 0, 1, 2, 3, 4, 5, 6, 7);
        }
#pragma unroll
        for (int i = 0; i < 4; ++i)
#pragma unroll
            for (int j = 0; j < 4; ++j)
                acc1[i][j] = __builtin_amdgcn_mfma_scale_f32_16x16x128_f8f6f4(
                    af[i], bf[j], acc1[i][j], 0, 0, 0, 127, 0, 127);
    }
}

// ---------------- K,V projections in ONE K-loop; emit PRODUCT p=tern(k)*tern(v) ----
// (k and v are never used individually downstream -- only kv enters the scan.)
__global__ __launch_bounds__(256, 2) void gemm128_kv(
    const u8* __restrict__ XK, const u8* __restrict__ Wk,
    const u8* __restrict__ XV, const u8* __restrict__ Wv,
    char* __restrict__ OP)
{
    __shared__ __align__(16) u8 lds[65536];
    int m0, n0;
    tile_coords128(blockIdx.x, m0, n0);

    f32x4 acc0[4][4] = {}, acc1[4][4] = {};
    gemm128_fp8_dual<false>(XK, Wk, XV, Wv, lds, m0, n0, acc0, acc1, nullptr, nullptr);

    const int lane = threadIdx.x & 63, wave = threadIdx.x >> 6;
    const int wm = wave >> 1, wn = wave & 1;
    const int mf = lane & 15, quad = lane >> 4;
#pragma unroll
    for (int i = 0; i < 4; ++i)
#pragma unroll
        for (int j = 0; j < 4; ++j)
#pragma unroll
            for (int e = 0; e < 4; ++e) {
                const int row = m0 + wm * 64 + i * 16 + quad * 4 + e;
                const int col = n0 + wn * 64 + j * 16 + mf;
                const float k = acc0[i][j][e];
                const float v = acc1[i][j][e];
                const int tk = (k > 0.5f) ? 1 : ((k < -0.5f) ? -1 : 0);
                const int tv = (v > 0.5f) ? 1 : ((v < -0.5f) ? -1 : 0);
                OP[(size_t)row * D_MODEL + col] = (char)(tk * tv);
            }
}

// ---------------- standalone scan over the int8 product stream ----------------
__global__ __launch_bounds__(512) void scan_kernel(
    const char* __restrict__ P8,
    const float* __restrict__ dw, const float* __restrict__ S0,
    u8* __restrict__ sall, float* __restrict__ sfinal)
{
    __shared__ unsigned int kvp[8][8][64];   // 16 KB: [chunk][word][ch]
    __shared__ float Lf[8][64];
    __shared__ float P[8][64];

    const int bid = blockIdx.x;            // 0..255
    const int db  = bid & 15, b = bid >> 4;
    const int ch  = threadIdx.x & 63;
    const int q   = threadIdx.x >> 6;      // T-chunk 0..7
    const int d   = db * 64 + ch;

    const float dec = 1.0f / (1.0f + __expf(-dw[d]));
    float c128 = dec;
#pragma unroll
    for (int i = 0; i < 7; i++) c128 *= c128;   // dec^128

    const size_t base = ((size_t)b * SEQ + q * 128) * D_MODEL + d;

    // pass 1: local scan (zero-init), batched product loads, 2-bit pack
    float S = 0.f;
    size_t idx = base;
    unsigned int w = 0;
    for (int t = 0; t < 128; t += 4, idx += 4 * D_MODEL) {
        const int p0 = P8[idx];
        const int p1 = P8[idx + 1 * D_MODEL];
        const int p2 = P8[idx + 2 * D_MODEL];
        const int p3 = P8[idx + 3 * D_MODEL];
        S = dec * S + (float)p0;
        S = dec * S + (float)p1;
        S = dec * S + (float)p2;
        S = dec * S + (float)p3;
        const int sh = 2 * (t & 15);
        w |= ((unsigned int)(p0 + 1) << sh) | ((unsigned int)(p1 + 1) << (sh + 2)) |
             ((unsigned int)(p2 + 1) << (sh + 4)) | ((unsigned int)(p3 + 1) << (sh + 6));
        if ((t & 15) == 12) { kvp[q][t >> 4][ch] = w; w = 0; }
    }

    Lf[q][ch] = S;
    __syncthreads();
    if (q == 0) {
        float p = S0[b * D_MODEL + d];      // true S_{-1}
        P[0][ch] = p;
#pragma unroll
        for (int j = 1; j < 8; ++j) {
            p = Lf[j - 1][ch] + c128 * p;
            P[j][ch] = p;
        }
        p = Lf[7][ch] + c128 * p;
        sfinal[b * D_MODEL + d] = p;
    }
    __syncthreads();

    // pass 2: replay from LDS with true incoming carry, store fp8
    float Sv = P[q][ch];
    idx = base;
    for (int t16 = 0; t16 < 8; ++t16) {
        const unsigned int pw = kvp[q][t16][ch];
#pragma unroll
        for (int j = 0; j < 16; ++j, idx += D_MODEL) {
            const float p = (float)((int)((pw >> (2 * j)) & 3) - 1);
            Sv = dec * Sv + p;
            const int enc = __builtin_amdgcn_cvt_pk_fp8_f32(Sv, 0.f, 0, false);
            sall[idx] = (u8)(enc & 255);
        }
    }
}

// ---------------- fused output: R-GEMM + O-GEMM in one K-loop, x prefetched ----------------
__global__ __launch_bounds__(256, 2) void gemm128_outR(
    const u8* __restrict__ XR, const u8* __restrict__ Wr,
    const u8* __restrict__ SA, const u8* __restrict__ Wo,
    const float* __restrict__ x, float* __restrict__ out)
{
    __shared__ __align__(16) u8 lds[65536];
    int m0, n0;
    tile_coords128(blockIdx.x, m0, n0);

    float xr_[64];
    f32x4 accR[4][4] = {}, acc[4][4] = {};
    gemm128_fp8_dual<true>(XR, Wr, SA, Wo, lds, m0, n0, accR, acc, x, xr_);

    const int lane = threadIdx.x & 63, wave = threadIdx.x >> 6;
    const int wm = wave >> 1, wn = wave & 1;
    const int mf = lane & 15, quad = lane >> 4;
#pragma unroll
    for (int i = 0; i < 4; ++i)
#pragma unroll
        for (int j = 0; j < 4; ++j)
#pragma unroll
            for (int e = 0; e < 4; ++e) {
                const int row = m0 + wm * 64 + i * 16 + quad * 4 + e;
                const int col = n0 + wn * 64 + j * 16 + mf;
                const size_t o = (size_t)row * D_MODEL + col;
                const float r = 1.0f / (1.0f + __expf(-accR[i][j][e]));
                out[o] = xr_[i * 16 + j * 4 + e] + r * acc[i][j][e];
            }
}

extern "C" void kernel_launch(void* const* d_in, const int* in_sizes, int n_in,
                              void* d_out, int out_size, void* d_ws, size_t ws_size,
                              hipStream_t stream) {
    const float* x     = (const float*)d_in[0];
    const float* S0    = (const float*)d_in[1];
    const float* gamma = (const float*)d_in[2];
    const float* beta  = (const float*)d_in[3];
    const float* tmk   = (const float*)d_in[4];
    const float* tmv   = (const float*)d_in[5];
    const float* tmr   = (const float*)d_in[6];
    const float* dw    = (const float*)d_in[7];
    const float* Wk    = (const float*)d_in[8];
    const float* Wv    = (const float*)d_in[9];
    const float* Wr    = (const float*)d_in[10];
    const float* Wo    = (const float*)d_in[11];
    float* out = (float*)d_out;

    const int WN = D_MODEL * D_MODEL;             // 1 MB fp8 per weight
    const size_t MATN = (size_t)NROWS * D_MODEL;  // 16 MB per fp8/int8 matrix

    u8* ws   = (u8*)d_ws;
    u8* Wk8  = ws;
    u8* Wv8  = Wk8 + WN;
    u8* Wr8  = Wv8 + WN;
    u8* Wo8  = Wr8 + WN;
    u8* XK8  = Wo8 + WN;
    u8* XV8  = XK8 + MATN;
    u8* XR8  = XV8 + MATN;
    char* P8 = (char*)(XR8 + MATN);
    u8* SA8  = (u8*)(P8 + MATN);

    conv_w4_kernel<<<dim3(256, 4), 256, 0, stream>>>(Wk, Wv, Wr, Wo, ws);

    lnmix_kernel<<<NROWS / 16, 256, 0, stream>>>(x, gamma, beta, tmk, tmv, tmr, XK8, XV8, XR8);

    // K,V projections interleaved; emit ternary product only
    gemm128_kv<<<1024, 256, 0, stream>>>(XK8, Wk8, XV8, Wv8, P8);

    // scan over the product stream (SA fp8 + S_final)
    scan_kernel<<<256, 512, 0, stream>>>(P8, dw, S0, SA8, out + MATN);

    // fused R-projection + output GEMM + residual (x prefetched in-loop)
    gemm128_outR<<<1024, 256, 0, stream>>>(XR8, Wr8, SA8, Wo8, x, out);
}